// Round 13
// baseline (127.151 us; speedup 1.0000x reference)
//
#include <hip/hip_runtime.h>
#include <hip/hip_bf16.h>

typedef _Float16 f16;
typedef _Float16 f16x2 __attribute__((ext_vector_type(2)));
typedef _Float16 f16x4 __attribute__((ext_vector_type(4)));
typedef _Float16 f16x8 __attribute__((ext_vector_type(8)));
typedef float f32x4 __attribute__((ext_vector_type(4)));

#define T_TOK 4096
#define V_N 32
#define H_N 256
#define LN_EPS_F 1e-5f

__device__ __forceinline__ void gload16(const f16* g, f16* l) {
    __builtin_amdgcn_global_load_lds(
        (const __attribute__((address_space(1))) void*)g,
        (__attribute__((address_space(3))) void*)l, 16, 0, 0);
}
__device__ __forceinline__ void gload16f(const float* g, float* l) {
    __builtin_amdgcn_global_load_lds(
        (const __attribute__((address_space(1))) void*)g,
        (__attribute__((address_space(3))) void*)l, 16, 0, 0);
}

// ---------------- prep: W2,Wg [v][k][n] f32 -> [v][n][k] f16 ----------------
__global__ __launch_bounds__(256) void prep_transpose(
    const float* __restrict__ W2, const float* __restrict__ Wg,
    f16* __restrict__ W2t, f16* __restrict__ Wgt)
{
    __shared__ float tile[64][65];
    int bid = blockIdx.x;
    int w = bid >> 9;
    int rem = bid & 511;
    int v = rem >> 4;
    int kt = (rem >> 2) & 3;
    int nt = rem & 3;
    const float* src = w ? Wg : W2;
    f16* dst = w ? Wgt : W2t;
    const float* base = src + ((size_t)v * H_N + (size_t)kt * 64) * H_N + nt * 64;
    int tid = threadIdx.x;
    #pragma unroll
    for (int p = 0; p < 16; ++p) {
        int idx = p * 256 + tid;
        int r = idx >> 6, c = idx & 63;
        tile[r][c] = base[(size_t)r * H_N + c];
    }
    __syncthreads();
    f16* obase = dst + ((size_t)v * H_N + (size_t)nt * 64) * H_N + kt * 64;
    #pragma unroll
    for (int p = 0; p < 16; ++p) {
        int idx = p * 256 + tid;
        int r = idx >> 6, c = idx & 63;
        obase[(size_t)r * H_N + c] = (f16)tile[c][r];
    }
}

// ---------------- prep: W1,b1 f32 -> f16 ----------------
__global__ __launch_bounds__(256) void prep_w1(
    const float* __restrict__ W1, const float* __restrict__ b1,
    f16* __restrict__ W1h, f16* __restrict__ b1h)
{
    int i = blockIdx.x * 256 + threadIdx.x;   // grid 32 -> 8192
    W1h[i] = (f16)W1[i];
    b1h[i] = (f16)b1[i];
}

// ---------------- kernel A: H2 = relu(x*W1+b1) @ W2 + b2, W2 LDS-resident ----
// Pure producer: writes H2g only. (Unchanged from r12 — verified on first call.)
__global__ __launch_bounds__(512) void grn_h2(
    const float* __restrict__ x,
    const f16* __restrict__ W1h, const f16* __restrict__ b1h,
    const f16* __restrict__ W2t, const float* __restrict__ b2,
    f16* __restrict__ H2g)          // [V][T][H]
{
    __shared__ f16 W2L[65536];      // 128 KB
    __shared__ f16 W1L[256], b1L[256];
    __shared__ float b2L[256];

    int bid = blockIdx.x;
    int xcd = bid & 7, idx = bid >> 3;
    int v  = (xcd << 2) + (idx & 3);
    int t0 = (idx >> 2) * 512;
    int tid = threadIdx.x;
    int w = tid >> 6, lane = tid & 63;
    int lo = lane & 15, hi = lane >> 4;
    int q = w & 3, th = w >> 2;

    const f16* W2v = W2t + ((size_t)v << 16);

    int cs = (lane & 31) ^ ((w * 2 + (lane >> 5)) & 7);
    #pragma unroll
    for (int r = 0; r < 16; ++r)
        gload16(W2v + ((size_t)(r * 16 + w * 2 + (lane >> 5)) << 8) + (cs << 3),
                &W2L[(r * 16 + w * 2) << 8]);
    if (w == 0 && lane < 32) gload16(W1h + (v << 8) + (lane << 3), W1L);
    if (w == 1 && lane < 32) gload16(b1h + (v << 8) + (lane << 3), b1L);
    if (w == 2) gload16f(b2 + (v << 8) + (lane << 2), b2L);

    float xs[4][4];
    #pragma unroll
    for (int st = 0; st < 4; ++st)
        #pragma unroll
        for (int g = 0; g < 4; ++g)
            xs[st][g] = x[(size_t)(t0 + st * 128 + th * 64 + g * 16 + lo) * V_N + v];

    __syncthreads();

    #pragma unroll
    for (int st = 0; st < 4; ++st) {
        int m0 = t0 + st * 128 + th * 64;
        f16x8 x8[4];
        #pragma unroll
        for (int g = 0; g < 4; ++g) {
            f16 xh = (f16)xs[st][g];
            x8[g] = f16x8{ xh, xh, xh, xh, xh, xh, xh, xh };
        }
        f32x4 acc[4][4] = {};
        #pragma unroll
        for (int s = 0; s < 8; ++s) {
            f16x8 w8 = *(const f16x8*)&W1L[(s << 5) + (hi << 3)];
            f16x8 c8 = *(const f16x8*)&b1L[(s << 5) + (hi << 3)];
            f16x8 hv[4];
            #pragma unroll
            for (int g = 0; g < 4; ++g) {
                f16x8 t = x8[g] * w8 + c8;
                #pragma unroll
                for (int j = 0; j < 8; ++j) t[j] = t[j] > (f16)0 ? t[j] : (f16)0;
                hv[g] = t;
            }
            #pragma unroll
            for (int nf = 0; nf < 4; ++nf) {
                f16x8 af = *(const f16x8*)&W2L[((q * 64 + nf * 16 + lo) << 8)
                                               + ((((s << 2) + hi) ^ (lo & 7)) << 3)];
                #pragma unroll
                for (int g = 0; g < 4; ++g)
                    acc[g][nf] = __builtin_amdgcn_mfma_f32_16x16x32_f16(
                        af, hv[g], acc[g][nf], 0, 0, 0);
            }
        }
        #pragma unroll
        for (int nf = 0; nf < 4; ++nf) {
            int n0 = q * 64 + nf * 16 + (hi << 2);
            f32x4 b4 = *(const f32x4*)&b2L[n0];
            #pragma unroll
            for (int g = 0; g < 4; ++g) {
                f32x4 h = acc[g][nf] + b4;
                f16x4 hh = { (f16)h[0], (f16)h[1], (f16)h[2], (f16)h[3] };
                *(f16x4*)&H2g[((size_t)v * T_TOK + m0 + g * 16 + lo) * H_N + n0] = hh;
            }
        }
    }
}

// ---------------- kernel B: gated -> LN -> score -> VO, NO in-place ----------------
// Reads H2g; writes VOg + scores. (VOg == H2g only in the small-ws fallback.)
__global__ __launch_bounds__(512) void grn_out(
    const f16* __restrict__ Wgt, const float* __restrict__ bg,
    const float* __restrict__ gamma, const float* __restrict__ beta,
    const float* __restrict__ Wa, const float* __restrict__ ba,
    const f16* H2g,                  // [V][T][H]  (no restrict: may alias VOg in fallback)
    f16* VOg,                        // [V][T][H]
    float* __restrict__ scores)      // [T][V]
{
    __shared__ f16 WgL[65536];       // 128 KB
    __shared__ float bgL[256], gmL[256], btL[256], waL[256];
    __shared__ float sqx[4][128][2];
    __shared__ float spxL[4][128];

    int bid = blockIdx.x;
    int xcd = bid & 7, idx = bid >> 3;
    int v  = (xcd << 2) + (idx & 3);
    int t0 = (idx >> 2) * 512;
    int tid = threadIdx.x;
    int w = tid >> 6, lane = tid & 63;
    int lo = lane & 15, hi = lane >> 4;
    int q = w & 3, th = w >> 2;

    const f16* Wgv = Wgt + ((size_t)v << 16);

    int cs = (lane & 31) ^ ((w * 2 + (lane >> 5)) & 7);
    #pragma unroll
    for (int r = 0; r < 16; ++r)
        gload16(Wgv + ((size_t)(r * 16 + w * 2 + (lane >> 5)) << 8) + (cs << 3),
                &WgL[(r * 16 + w * 2) << 8]);
    if (w == 0) gload16f(bg    + (v << 8) + (lane << 2), bgL);
    if (w == 1) gload16f(gamma + (v << 8) + (lane << 2), gmL);
    if (w == 2) gload16f(beta  + (v << 8) + (lane << 2), btL);
    if (w == 3) gload16f(Wa + (lane << 2), waL);
    float bav = ba[0];

    __syncthreads();

    #pragma unroll
    for (int st = 0; st < 4; ++st) {
        int m0 = t0 + st * 128 + th * 64;
        const f16* rp0 = H2g + ((size_t)v * T_TOK + m0 + 0 * 16 + lo) * H_N;
        const f16* rp1 = H2g + ((size_t)v * T_TOK + m0 + 1 * 16 + lo) * H_N;
        const f16* rp2 = H2g + ((size_t)v * T_TOK + m0 + 2 * 16 + lo) * H_N;
        const f16* rp3 = H2g + ((size_t)v * T_TOK + m0 + 3 * 16 + lo) * H_N;
        const f16* rp[4] = { rp0, rp1, rp2, rp3 };
        f16* vr0 = VOg + ((size_t)v * T_TOK + m0 + 0 * 16 + lo) * H_N;
        f16* vr1 = VOg + ((size_t)v * T_TOK + m0 + 1 * 16 + lo) * H_N;
        f16* vr2 = VOg + ((size_t)v * T_TOK + m0 + 2 * 16 + lo) * H_N;
        f16* vr3 = VOg + ((size_t)v * T_TOK + m0 + 3 * 16 + lo) * H_N;
        f16* vr[4] = { vr0, vr1, vr2, vr3 };

        f16x8 bf0[4], bf1[4], bf2[4];
        #pragma unroll
        for (int g = 0; g < 4; ++g) {
            bf0[g] = *(const f16x8*)&rp[g][0 * 32 + (hi << 3)];
            bf1[g] = *(const f16x8*)&rp[g][1 * 32 + (hi << 3)];
            bf2[g] = *(const f16x8*)&rp[g][2 * 32 + (hi << 3)];
        }
        f32x4 acc[4][4] = {};

#define BSTEP(BF, S)                                                             \
        {                                                                        \
            _Pragma("unroll")                                                    \
            for (int nf = 0; nf < 4; ++nf) {                                     \
                f16x8 af = *(const f16x8*)&WgL[((q * 64 + nf * 16 + lo) << 8)    \
                                     + (((((S) << 2) + hi) ^ (lo & 7)) << 3)];   \
                _Pragma("unroll")                                                \
                for (int g = 0; g < 4; ++g)                                      \
                    acc[g][nf] = __builtin_amdgcn_mfma_f32_16x16x32_f16(         \
                        af, BF[g], acc[g][nf], 0, 0, 0);                         \
            }                                                                    \
            if ((S) < 5) {                                                       \
                _Pragma("unroll")                                                \
                for (int g = 0; g < 4; ++g)                                      \
                    BF[g] = *(const f16x8*)&rp[g][((S) + 3) * 32 + (hi << 3)];   \
            }                                                                    \
        }

        BSTEP(bf0, 0) BSTEP(bf1, 1) BSTEP(bf2, 2)
        BSTEP(bf0, 3) BSTEP(bf1, 4) BSTEP(bf2, 5)
        BSTEP(bf0, 6) BSTEP(bf1, 7)
#undef BSTEP

        float sr[4] = {}, qr[4] = {};
        #pragma unroll
        for (int g = 0; g < 4; ++g) {
            #pragma unroll
            for (int nf = 0; nf < 4; ++nf) {
                int n0 = q * 64 + nf * 16 + (hi << 2);
                f32x4 bgv = *(const f32x4*)&bgL[n0];
                f16x4 h2v = *(const f16x4*)&rp[g][n0];
                #pragma unroll
                for (int r = 0; r < 4; ++r) {
                    float a = acc[g][nf][r] + bgv[r];
                    float sg = 1.f / (1.f + __expf(-a));
                    float val = sg * (float)h2v[r];
                    acc[g][nf][r] = val;
                    sr[g] += val; qr[g] += val * val;
                }
            }
            sr[g] += __shfl_xor(sr[g], 16); sr[g] += __shfl_xor(sr[g], 32);
            qr[g] += __shfl_xor(qr[g], 16); qr[g] += __shfl_xor(qr[g], 32);
        }
        if (hi == 0) {
            #pragma unroll
            for (int g = 0; g < 4; ++g) {
                sqx[q][th * 64 + g * 16 + lo][0] = sr[g];
                sqx[q][th * 64 + g * 16 + lo][1] = qr[g];
            }
        }
        __syncthreads();
        float mu[4], inv[4];
        #pragma unroll
        for (int g = 0; g < 4; ++g) {
            int tk = th * 64 + g * 16 + lo;
            float s_ = sqx[0][tk][0] + sqx[1][tk][0] + sqx[2][tk][0] + sqx[3][tk][0];
            float q_ = sqx[0][tk][1] + sqx[1][tk][1] + sqx[2][tk][1] + sqx[3][tk][1];
            mu[g] = s_ * (1.f / 256.f);
            float var = q_ * (1.f / 256.f) - mu[g] * mu[g];
            inv[g] = rsqrtf(var + LN_EPS_F);
        }
        float sp[4] = {};
        #pragma unroll
        for (int g = 0; g < 4; ++g) {
            #pragma unroll
            for (int nf = 0; nf < 4; ++nf) {
                int n0 = q * 64 + nf * 16 + (hi << 2);
                f32x4 gm = *(const f32x4*)&gmL[n0];
                f32x4 bt = *(const f32x4*)&btL[n0];
                f32x4 wa = *(const f32x4*)&waL[n0];
                f16x4 ov;
                #pragma unroll
                for (int r = 0; r < 4; ++r) {
                    float o = (acc[g][nf][r] - mu[g]) * inv[g] * gm[r] + bt[r];
                    sp[g] += o * wa[r];
                    ov[r] = (f16)o;
                }
                *(f16x4*)&vr[g][n0] = ov;
            }
            sp[g] += __shfl_xor(sp[g], 16); sp[g] += __shfl_xor(sp[g], 32);
        }
        if (hi == 0) {
            #pragma unroll
            for (int g = 0; g < 4; ++g) spxL[q][th * 64 + g * 16 + lo] = sp[g];
        }
        __syncthreads();
        if (q == 0 && hi == 0) {
            #pragma unroll
            for (int g = 0; g < 4; ++g) {
                int tk = th * 64 + g * 16 + lo;
                scores[(size_t)(t0 + st * 128 + tk) * V_N + v] =
                    spxL[0][tk] + spxL[1][tk] + spxL[2][tk] + spxL[3][tk] + bav;
            }
        }
    }
}

// ---------------- softmax over V + pooled sum ----------------
__global__ __launch_bounds__(128) void pool(
    const f16* __restrict__ VO,       // [V][T][H]
    const float* __restrict__ scores, // [T][V]
    float* __restrict__ out)          // [T*H] vsn, then [T*V] attn
{
    int t = blockIdx.x, tid = threadIdx.x;
    __shared__ float sc[V_N];
    if (tid < V_N) sc[tid] = scores[t * V_N + tid];
    __syncthreads();
    float mx = -1e30f;
    #pragma unroll
    for (int v = 0; v < V_N; ++v) mx = fmaxf(mx, sc[v]);
    float e[V_N];
    float sum = 0.f;
    #pragma unroll
    for (int v = 0; v < V_N; ++v) { e[v] = __expf(sc[v] - mx); sum += e[v]; }
    float isum = 1.f / sum;
    float a0 = 0.f, a1 = 0.f;
    #pragma unroll
    for (int v = 0; v < V_N; ++v) {
        f16x2 vv = *(const f16x2*)&VO[((size_t)v * T_TOK + t) * H_N + tid * 2];
        float ww = e[v] * isum;
        a0 = fmaf((float)vv[0], ww, a0);
        a1 = fmaf((float)vv[1], ww, a1);
    }
    *(float2*)&out[(size_t)t * H_N + tid * 2] = make_float2(a0, a1);
    if (tid < V_N)
        out[(size_t)T_TOK * H_N + (size_t)t * V_N + tid] = e[tid] * isum;
}

extern "C" void kernel_launch(void* const* d_in, const int* in_sizes, int n_in,
                              void* d_out, int out_size, void* d_ws, size_t ws_size,
                              hipStream_t stream)
{
    const float* x     = (const float*)d_in[0];
    const float* W1    = (const float*)d_in[1];
    const float* b1    = (const float*)d_in[2];
    const float* W2    = (const float*)d_in[3];
    const float* b2    = (const float*)d_in[4];
    const float* Wg    = (const float*)d_in[5];
    const float* bg    = (const float*)d_in[6];
    const float* gamma = (const float*)d_in[7];
    const float* beta  = (const float*)d_in[8];
    const float* Wa    = (const float*)d_in[9];
    const float* ba    = (const float*)d_in[10];
    float* out = (float*)d_out;

    char* ws = (char*)d_ws;
    f16* W2t = (f16*)ws;                                        // [0, 4M)
    f16* Wgt = (f16*)(ws + ((size_t)4 << 20));                  // [4M, 8M)
    f16* H2g = (f16*)(ws + ((size_t)8 << 20));                  // [8M, 72M)
    float* scores = (float*)(ws + ((size_t)72 << 20));          // 512 KB
    f16* W1h = (f16*)(ws + ((size_t)72 << 20) + (512 << 10));   // 16 KB
    f16* b1h = (f16*)(ws + ((size_t)72 << 20) + (528 << 10));   // 16 KB
    // separate VO buffer when workspace allows (expected path); else in-place
    const size_t NEED = ((size_t)137 << 20);
    f16* VOg = (ws_size >= NEED) ? (f16*)(ws + ((size_t)73 << 20)) : H2g;

    prep_transpose<<<1024, 256, 0, stream>>>(W2, Wg, W2t, Wgt);
    prep_w1<<<32, 256, 0, stream>>>(W1, b1, W1h, b1h);
    grn_h2<<<256, 512, 0, stream>>>(x, W1h, b1h, W2t, b2, H2g);
    grn_out<<<256, 512, 0, stream>>>(Wgt, bg, gamma, beta, Wa, ba, H2g, VOg, scores);
    pool<<<4096, 128, 0, stream>>>(VOg, scores, out);
}

// Round 14
// 119.685 us; speedup vs baseline: 1.0624x; 1.0624x over previous
//
#include <hip/hip_runtime.h>
#include <hip/hip_bf16.h>

typedef _Float16 f16;
typedef _Float16 f16x2 __attribute__((ext_vector_type(2)));
typedef _Float16 f16x4 __attribute__((ext_vector_type(4)));
typedef _Float16 f16x8 __attribute__((ext_vector_type(8)));
typedef float f32x4 __attribute__((ext_vector_type(4)));

#define T_TOK 4096
#define V_N 32
#define H_N 256
#define LN_EPS_F 1e-5f

__device__ __forceinline__ void gload16(const f16* g, f16* l) {
    __builtin_amdgcn_global_load_lds(
        (const __attribute__((address_space(1))) void*)g,
        (__attribute__((address_space(3))) void*)l, 16, 0, 0);
}
__device__ __forceinline__ void gload16f(const float* g, float* l) {
    __builtin_amdgcn_global_load_lds(
        (const __attribute__((address_space(1))) void*)g,
        (__attribute__((address_space(3))) void*)l, 16, 0, 0);
}

// ---------------- prep: W2,Wg [v][k][n] f32 -> [v][n][k] f16 ----------------
__global__ __launch_bounds__(256) void prep_transpose(
    const float* __restrict__ W2, const float* __restrict__ Wg,
    f16* __restrict__ W2t, f16* __restrict__ Wgt)
{
    __shared__ float tile[64][65];
    int bid = blockIdx.x;
    int w = bid >> 9;
    int rem = bid & 511;
    int v = rem >> 4;
    int kt = (rem >> 2) & 3;
    int nt = rem & 3;
    const float* src = w ? Wg : W2;
    f16* dst = w ? Wgt : W2t;
    const float* base = src + ((size_t)v * H_N + (size_t)kt * 64) * H_N + nt * 64;
    int tid = threadIdx.x;
    #pragma unroll
    for (int p = 0; p < 16; ++p) {
        int idx = p * 256 + tid;
        int r = idx >> 6, c = idx & 63;
        tile[r][c] = base[(size_t)r * H_N + c];
    }
    __syncthreads();
    f16* obase = dst + ((size_t)v * H_N + (size_t)nt * 64) * H_N + kt * 64;
    #pragma unroll
    for (int p = 0; p < 16; ++p) {
        int idx = p * 256 + tid;
        int r = idx >> 6, c = idx & 63;
        obase[(size_t)r * H_N + c] = (f16)tile[c][r];
    }
}

// ---------------- prep: W1,b1 f32 -> f16 ----------------
__global__ __launch_bounds__(256) void prep_w1(
    const float* __restrict__ W1, const float* __restrict__ b1,
    f16* __restrict__ W1h, f16* __restrict__ b1h)
{
    int i = blockIdx.x * 256 + threadIdx.x;   // grid 32 -> 8192
    W1h[i] = (f16)W1[i];
    b1h[i] = (f16)b1[i];
}

// ---------------- kernel A: H2 = relu(x*W1+b1) @ W2 + b2, W2 LDS-resident ----
// (unchanged from r13 — verified)
__global__ __launch_bounds__(512) void grn_h2(
    const float* __restrict__ x,
    const f16* __restrict__ W1h, const f16* __restrict__ b1h,
    const f16* __restrict__ W2t, const float* __restrict__ b2,
    f16* __restrict__ H2g)          // [V][T][H]
{
    __shared__ f16 W2L[65536];      // 128 KB
    __shared__ f16 W1L[256], b1L[256];
    __shared__ float b2L[256];

    int bid = blockIdx.x;
    int xcd = bid & 7, idx = bid >> 3;
    int v  = (xcd << 2) + (idx & 3);
    int t0 = (idx >> 2) * 512;
    int tid = threadIdx.x;
    int w = tid >> 6, lane = tid & 63;
    int lo = lane & 15, hi = lane >> 4;
    int q = w & 3, th = w >> 2;

    const f16* W2v = W2t + ((size_t)v << 16);

    int cs = (lane & 31) ^ ((w * 2 + (lane >> 5)) & 7);
    #pragma unroll
    for (int r = 0; r < 16; ++r)
        gload16(W2v + ((size_t)(r * 16 + w * 2 + (lane >> 5)) << 8) + (cs << 3),
                &W2L[(r * 16 + w * 2) << 8]);
    if (w == 0 && lane < 32) gload16(W1h + (v << 8) + (lane << 3), W1L);
    if (w == 1 && lane < 32) gload16(b1h + (v << 8) + (lane << 3), b1L);
    if (w == 2) gload16f(b2 + (v << 8) + (lane << 2), b2L);

    float xs[4][4];
    #pragma unroll
    for (int st = 0; st < 4; ++st)
        #pragma unroll
        for (int g = 0; g < 4; ++g)
            xs[st][g] = x[(size_t)(t0 + st * 128 + th * 64 + g * 16 + lo) * V_N + v];

    __syncthreads();

    #pragma unroll
    for (int st = 0; st < 4; ++st) {
        int m0 = t0 + st * 128 + th * 64;
        f16x8 x8[4];
        #pragma unroll
        for (int g = 0; g < 4; ++g) {
            f16 xh = (f16)xs[st][g];
            x8[g] = f16x8{ xh, xh, xh, xh, xh, xh, xh, xh };
        }
        f32x4 acc[4][4] = {};
        #pragma unroll
        for (int s = 0; s < 8; ++s) {
            f16x8 w8 = *(const f16x8*)&W1L[(s << 5) + (hi << 3)];
            f16x8 c8 = *(const f16x8*)&b1L[(s << 5) + (hi << 3)];
            f16x8 hv[4];
            #pragma unroll
            for (int g = 0; g < 4; ++g) {
                f16x8 t = x8[g] * w8 + c8;
                #pragma unroll
                for (int j = 0; j < 8; ++j) t[j] = t[j] > (f16)0 ? t[j] : (f16)0;
                hv[g] = t;
            }
            #pragma unroll
            for (int nf = 0; nf < 4; ++nf) {
                f16x8 af = *(const f16x8*)&W2L[((q * 64 + nf * 16 + lo) << 8)
                                               + ((((s << 2) + hi) ^ (lo & 7)) << 3)];
                #pragma unroll
                for (int g = 0; g < 4; ++g)
                    acc[g][nf] = __builtin_amdgcn_mfma_f32_16x16x32_f16(
                        af, hv[g], acc[g][nf], 0, 0, 0);
            }
        }
        #pragma unroll
        for (int nf = 0; nf < 4; ++nf) {
            int n0 = q * 64 + nf * 16 + (hi << 2);
            f32x4 b4 = *(const f32x4*)&b2L[n0];
            #pragma unroll
            for (int g = 0; g < 4; ++g) {
                f32x4 h = acc[g][nf] + b4;
                f16x4 hh = { (f16)h[0], (f16)h[1], (f16)h[2], (f16)h[3] };
                *(f16x4*)&H2g[((size_t)v * T_TOK + m0 + g * 16 + lo) * H_N + n0] = hh;
            }
        }
    }
}

// ---------------- kernel B v2: Wg in REGISTERS, H2 tile in LDS (staged once) ----
// grid 512 = (xcd, v, 16 chunks of 256 tokens), 512 thr = 8 waves.
// Wave w owns n-slice [32w, 32w+32): afW[8][2] (64 VGPR) loaded once from L2.
// H2 64-token tiles double-buffered in LDS via global_load_lds (chunk-XOR c^(r&31));
// bf + gating reads from LDS. H2 read from global EXACTLY once. 2 barriers/tile.
__global__ __launch_bounds__(512, 2) void grn_out(
    const f16* __restrict__ Wgt, const float* __restrict__ bg,
    const float* __restrict__ gamma, const float* __restrict__ beta,
    const float* __restrict__ Wa, const float* __restrict__ ba,
    const f16* H2g,                  // may alias VOg in small-ws fallback
    f16* VOg,
    float* __restrict__ scores)      // [T][V]
{
    __shared__ __align__(16) f16 H2L[2][64 * 256];  // 2 x 32 KB
    __shared__ float bgL[256], gmL[256], btL[256], waL[256];
    __shared__ float sqx[8][4][16][2];              // 4 KB
    __shared__ float spxL[8][4][16];                // 2 KB

    int bid = blockIdx.x;
    int xcd = bid & 7, idx = bid >> 3;
    int v  = (xcd << 2) + (idx & 3);
    int t0 = (idx >> 2) * 256;                      // 16 chunks x 256 tokens
    int tid = threadIdx.x;
    int w = tid >> 6, lane = tid & 63;
    int lo = lane & 15, hi = lane >> 4;

    const f16* Wgv = Wgt + ((size_t)v << 16);

    // ---- Wg n-slice -> registers (16 x f16x8 = 64 VGPR), fully static ----
    f16x8 afW[8][2];
    #pragma unroll
    for (int s = 0; s < 8; ++s)
        #pragma unroll
        for (int nf = 0; nf < 2; ++nf)
            afW[s][nf] = *(const f16x8*)&Wgv[((w * 32 + nf * 16 + lo) << 8)
                                             + (s << 5) + (hi << 3)];

    if (w == 0) gload16f(bg    + (v << 8) + (lane << 2), bgL);
    if (w == 1) gload16f(gamma + (v << 8) + (lane << 2), gmL);
    if (w == 2) gload16f(beta  + (v << 8) + (lane << 2), btL);
    if (w == 3) gload16f(Wa + (lane << 2), waL);
    float bav = ba[0];

    // stage 64-token tile into H2L[buf]; wave w stages rows [w*8, w*8+8).
    // slot c of row r holds global 16B-chunk c ^ (r&31)  [involution]
    auto stage = [&](int tile, int buf) {
        #pragma unroll
        for (int i = 0; i < 4; ++i) {
            int r = w * 8 + i * 2 + (lane >> 5);
            int cg = (lane & 31) ^ (r & 31);
            gload16(H2g + ((size_t)v * T_TOK + t0 + tile * 64 + r) * H_N + (cg << 3),
                    &H2L[buf][(w * 8 + i * 2) << 8]);
        }
    };

    stage(0, 0);
    asm volatile("s_waitcnt vmcnt(0) lgkmcnt(0)" ::: "memory");
    __builtin_amdgcn_s_barrier();

    #pragma unroll
    for (int t = 0; t < 4; ++t) {
        const int buf = t & 1;
        if (t < 3) stage(t + 1, buf ^ 1);           // overlapped with whole tile
        int m0 = t0 + t * 64;

        f32x4 acc[4][2] = {};   // [g][nf]: token = g*16+lo, n = w*32+nf*16+hi*4+r
        #pragma unroll
        for (int s = 0; s < 8; ++s) {
            #pragma unroll
            for (int g = 0; g < 4; ++g) {
                int tok = g * 16 + lo;
                int slot = ((s << 2) + hi) ^ (tok & 31);
                f16x8 bf = *(const f16x8*)&H2L[buf][(tok << 8) + (slot << 3)];
                acc[g][0] = __builtin_amdgcn_mfma_f32_16x16x32_f16(
                    afW[s][0], bf, acc[g][0], 0, 0, 0);
                acc[g][1] = __builtin_amdgcn_mfma_f32_16x16x32_f16(
                    afW[s][1], bf, acc[g][1], 0, 0, 0);
            }
        }

        // ---- gating (H2 from LDS) + LN partials ----
        float sr[4] = {}, qr[4] = {};
        #pragma unroll
        for (int g = 0; g < 4; ++g) {
            int tok = g * 16 + lo;
            #pragma unroll
            for (int nf = 0; nf < 2; ++nf) {
                int n0 = w * 32 + nf * 16 + (hi << 2);
                f32x4 bgv = *(const f32x4*)&bgL[n0];
                int slot = ((w << 2) + (nf << 1) + (hi >> 1)) ^ (tok & 31);
                f16x4 h2v = *(const f16x4*)&H2L[buf][(tok << 8) + (slot << 3)
                                                     + ((hi & 1) << 2)];
                #pragma unroll
                for (int r = 0; r < 4; ++r) {
                    float a = acc[g][nf][r] + bgv[r];
                    float sg = 1.f / (1.f + __expf(-a));
                    float val = sg * (float)h2v[r];
                    acc[g][nf][r] = val;
                    sr[g] += val; qr[g] += val * val;
                }
            }
            sr[g] += __shfl_xor(sr[g], 16); sr[g] += __shfl_xor(sr[g], 32);
            qr[g] += __shfl_xor(qr[g], 16); qr[g] += __shfl_xor(qr[g], 32);
        }
        if (hi == 0) {
            #pragma unroll
            for (int g = 0; g < 4; ++g) {
                sqx[w][g][lo][0] = sr[g];
                sqx[w][g][lo][1] = qr[g];
            }
        }
        __syncthreads();

        float mu[4], inv[4];
        #pragma unroll
        for (int g = 0; g < 4; ++g) {
            float st = 0.f, qt = 0.f;
            #pragma unroll
            for (int ww = 0; ww < 8; ++ww) {
                st += sqx[ww][g][lo][0];
                qt += sqx[ww][g][lo][1];
            }
            mu[g] = st * (1.f / 256.f);
            float var = qt * (1.f / 256.f) - mu[g] * mu[g];
            inv[g] = rsqrtf(var + LN_EPS_F);
        }

        // ---- normalize + score partial + VO write (8 global stores/thread) ----
        float sp[4] = {};
        #pragma unroll
        for (int g = 0; g < 4; ++g) {
            f16* VOr = VOg + ((size_t)v * T_TOK + m0 + g * 16 + lo) * H_N;
            #pragma unroll
            for (int nf = 0; nf < 2; ++nf) {
                int n0 = w * 32 + nf * 16 + (hi << 2);
                f32x4 gm = *(const f32x4*)&gmL[n0];
                f32x4 bt = *(const f32x4*)&btL[n0];
                f32x4 wa = *(const f32x4*)&waL[n0];
                f16x4 ov;
                #pragma unroll
                for (int r = 0; r < 4; ++r) {
                    float o = (acc[g][nf][r] - mu[g]) * inv[g] * gm[r] + bt[r];
                    sp[g] += o * wa[r];
                    ov[r] = (f16)o;
                }
                *(f16x4*)&VOr[n0] = ov;
            }
            sp[g] += __shfl_xor(sp[g], 16); sp[g] += __shfl_xor(sp[g], 32);
        }
        if (hi == 0) {
            #pragma unroll
            for (int g = 0; g < 4; ++g) spxL[w][g][lo] = sp[g];
        }
        // combined barrier: spx visible + stage(t+1) loads (4 oldest) complete;
        // the 8 VO stores may stay in flight (counted vmcnt(8))
        asm volatile("s_waitcnt vmcnt(8) lgkmcnt(0)" ::: "memory");
        __builtin_amdgcn_s_barrier();

        if (w == 0 && hi == 0) {
            #pragma unroll
            for (int g = 0; g < 4; ++g) {
                float tsum = bav;
                #pragma unroll
                for (int ww = 0; ww < 8; ++ww) tsum += spxL[ww][g][lo];
                scores[(size_t)(m0 + g * 16 + lo) * V_N + v] = tsum;
            }
        }
    }
}

// ---------------- softmax over V + pooled sum ----------------
__global__ __launch_bounds__(128) void pool(
    const f16* __restrict__ VO,       // [V][T][H]
    const float* __restrict__ scores, // [T][V]
    float* __restrict__ out)          // [T*H] vsn, then [T*V] attn
{
    int t = blockIdx.x, tid = threadIdx.x;
    __shared__ float sc[V_N];
    if (tid < V_N) sc[tid] = scores[t * V_N + tid];
    __syncthreads();
    float mx = -1e30f;
    #pragma unroll
    for (int v = 0; v < V_N; ++v) mx = fmaxf(mx, sc[v]);
    float e[V_N];
    float sum = 0.f;
    #pragma unroll
    for (int v = 0; v < V_N; ++v) { e[v] = __expf(sc[v] - mx); sum += e[v]; }
    float isum = 1.f / sum;
    float a0 = 0.f, a1 = 0.f;
    #pragma unroll
    for (int v = 0; v < V_N; ++v) {
        f16x2 vv = *(const f16x2*)&VO[((size_t)v * T_TOK + t) * H_N + tid * 2];
        float ww = e[v] * isum;
        a0 = fmaf((float)vv[0], ww, a0);
        a1 = fmaf((float)vv[1], ww, a1);
    }
    *(float2*)&out[(size_t)t * H_N + tid * 2] = make_float2(a0, a1);
    if (tid < V_N)
        out[(size_t)T_TOK * H_N + (size_t)t * V_N + tid] = e[tid] * isum;
}

extern "C" void kernel_launch(void* const* d_in, const int* in_sizes, int n_in,
                              void* d_out, int out_size, void* d_ws, size_t ws_size,
                              hipStream_t stream)
{
    const float* x     = (const float*)d_in[0];
    const float* W1    = (const float*)d_in[1];
    const float* b1    = (const float*)d_in[2];
    const float* W2    = (const float*)d_in[3];
    const float* b2    = (const float*)d_in[4];
    const float* Wg    = (const float*)d_in[5];
    const float* bg    = (const float*)d_in[6];
    const float* gamma = (const float*)d_in[7];
    const float* beta  = (const float*)d_in[8];
    const float* Wa    = (const float*)d_in[9];
    const float* ba    = (const float*)d_in[10];
    float* out = (float*)d_out;

    char* ws = (char*)d_ws;
    f16* W2t = (f16*)ws;                                        // [0, 4M)
    f16* Wgt = (f16*)(ws + ((size_t)4 << 20));                  // [4M, 8M)
    f16* H2g = (f16*)(ws + ((size_t)8 << 20));                  // [8M, 72M)
    float* scores = (float*)(ws + ((size_t)72 << 20));          // 512 KB
    f16* W1h = (f16*)(ws + ((size_t)72 << 20) + (512 << 10));   // 16 KB
    f16* b1h = (f16*)(ws + ((size_t)72 << 20) + (528 << 10));   // 16 KB
    const size_t NEED = ((size_t)137 << 20);
    f16* VOg = (ws_size >= NEED) ? (f16*)(ws + ((size_t)73 << 20)) : H2g;

    prep_transpose<<<1024, 256, 0, stream>>>(W2, Wg, W2t, Wgt);
    prep_w1<<<32, 256, 0, stream>>>(W1, b1, W1h, b1h);
    grn_h2<<<256, 512, 0, stream>>>(x, W1h, b1h, W2t, b2, H2g);
    grn_out<<<512, 512, 0, stream>>>(Wgt, bg, gamma, beta, Wa, ba, H2g, VOg, scores);
    pool<<<4096, 128, 0, stream>>>(VOg, scores, out);
}